// Round 12
// baseline (1428.611 us; speedup 1.0000x reference)
//
#include <hip/hip_runtime.h>
#include <hip/hip_fp16.h>

#define HD 384
#define HHD 192

using bf16x8 = __attribute__((ext_vector_type(8))) short;
using f32x4  = __attribute__((ext_vector_type(4))) float;

__device__ __forceinline__ float gelu_f(float x) {
    return 0.5f * x * (1.0f + erff(x * 0.70710678118654752f));
}

__device__ __forceinline__ float sigmoid_f(float x) {
    return 1.0f / (1.0f + expf(-x));
}

__device__ __forceinline__ void fma8(float* a, uint4 q, float v) {
    const __half2* h = reinterpret_cast<const __half2*>(&q);
    #pragma unroll
    for (int k = 0; k < 4; ++k) {
        float2 f = __half22float2(h[k]);
        a[2 * k]     = fmaf(v, f.x, a[2 * k]);
        a[2 * k + 1] = fmaf(v, f.y, a[2 * k + 1]);
    }
}

// ---------------- CSR build ----------------
__global__ __launch_bounds__(256) void hist_rows(
        const int* __restrict__ rows, int* __restrict__ cnt, int nnz) {
    int e = blockIdx.x * blockDim.x + threadIdx.x;
    if (e < nnz) atomicAdd(&cnt[rows[e]], 1);
}

__global__ __launch_bounds__(256) void scan_local(
        const int* __restrict__ cnt, int* __restrict__ rp,
        int* __restrict__ bsum, int n) {
    __shared__ int wsum[4];
    int i = blockIdx.x * 256 + threadIdx.x;
    int lane = threadIdx.x & 63, wv = threadIdx.x >> 6;
    int v = (i < n) ? cnt[i] : 0;
    int s = v;
    #pragma unroll
    for (int o = 1; o < 64; o <<= 1) {
        int t = __shfl_up(s, o);
        if (lane >= o) s += t;
    }
    if (lane == 63) wsum[wv] = s;
    __syncthreads();
    int woff = 0;
    for (int w = 0; w < wv; ++w) woff += wsum[w];
    if (i < n) rp[i] = woff + s - v;
    if (threadIdx.x == 255) bsum[blockIdx.x] = woff + s;
}

__global__ __launch_bounds__(256) void scan_bsums(
        const int* __restrict__ bsum, int* __restrict__ boff,
        int nb, int* __restrict__ total_out) {
    __shared__ int tmp[256];
    int tid = threadIdx.x;
    int v = (tid < nb) ? bsum[tid] : 0;
    tmp[tid] = v;
    __syncthreads();
    for (int o = 1; o < 256; o <<= 1) {
        int t = (tid >= o) ? tmp[tid - o] : 0;
        __syncthreads();
        tmp[tid] += t;
        __syncthreads();
    }
    if (tid < nb) boff[tid] = tmp[tid] - v;
    if (tid == nb - 1) *total_out = tmp[tid];
}

__global__ __launch_bounds__(256) void scan_add(
        int* __restrict__ rp, const int* __restrict__ boff, int n) {
    int i = blockIdx.x * 256 + threadIdx.x;
    if (i < n) rp[i] += boff[i >> 8];
}

__global__ __launch_bounds__(256) void csr_scatter(
        const int* __restrict__ rows, const int* __restrict__ cols,
        const float* __restrict__ vals, const int* __restrict__ rp,
        int* __restrict__ fill, int2* __restrict__ ev, int nnz) {
    int e = blockIdx.x * blockDim.x + threadIdx.x;
    if (e >= nnz) return;
    int r = rows[e];
    int pos = rp[r] + atomicAdd(&fill[r], 1);
    ev[pos] = make_int2(cols[e], __float_as_int(vals[e]));
}

// ---------------- fp32 -> fp16 convert ----------------
__global__ __launch_bounds__(256) void cvt_fp16(
        const float* __restrict__ in, __half2* __restrict__ out, int n2) {
    int i = blockIdx.x * blockDim.x + threadIdx.x;
    if (i >= n2) return;
    float2 v = reinterpret_cast<const float2*>(in)[i];
    out[i] = __floats2half2_rn(v.x, v.y);
}

// ---------------- XCD-sliced SpMM gather ----------------
// blockIdx.x % 8 = feature slice (96B of each 768B table row) -> lands on one XCD
// (round-robin dispatch), whose 4MB L2 holds the whole 3.84MB slice.
// 64 rows/block x 6 lanes x 16B. Per-row direct edge loop (no padding).
// OUTF32: write fp32 (doc passes) else fp16. MIX: out = 0.35*aux + 0.65*acc.
template<bool OUTF32, bool MIX>
__global__ __launch_bounds__(384) void spmm_sliced(
        const int* __restrict__ rp, const int2* __restrict__ ev,
        const __half* __restrict__ in, void* __restrict__ outv,
        const float* __restrict__ aux, int nrows) {
    const int s = blockIdx.x & 7;
    const int g = blockIdx.x >> 3;
    const int rr = threadIdx.x / 6;
    const int t  = threadIdx.x % 6;
    const int r  = g * 64 + rr;
    if (r >= nrows) return;
    const int p0 = rp[r], p1 = rp[r + 1];
    const int off = s * 48 + t * 8;                  // halfs within row
    const __half* base = in + off;
    float a[8] = {0.f, 0.f, 0.f, 0.f, 0.f, 0.f, 0.f, 0.f};
    int p = p0;
    for (; p + 4 <= p1; p += 4) {
        int2 e0 = ev[p], e1 = ev[p + 1], e2 = ev[p + 2], e3 = ev[p + 3];
        uint4 q0 = *reinterpret_cast<const uint4*>(base + (size_t)e0.x * HD);
        uint4 q1 = *reinterpret_cast<const uint4*>(base + (size_t)e1.x * HD);
        uint4 q2 = *reinterpret_cast<const uint4*>(base + (size_t)e2.x * HD);
        uint4 q3 = *reinterpret_cast<const uint4*>(base + (size_t)e3.x * HD);
        fma8(a, q0, __int_as_float(e0.y));
        fma8(a, q1, __int_as_float(e1.y));
        fma8(a, q2, __int_as_float(e2.y));
        fma8(a, q3, __int_as_float(e3.y));
    }
    for (; p < p1; ++p) {
        int2 e = ev[p];
        uint4 q = *reinterpret_cast<const uint4*>(base + (size_t)e.x * HD);
        fma8(a, q, __int_as_float(e.y));
    }
    if constexpr (OUTF32) {
        float* out = (float*)outv + (size_t)r * HD + off;
        if constexpr (MIX) {
            const float* ax = aux + (size_t)r * HD + off;
            float4 x0 = *reinterpret_cast<const float4*>(ax);
            float4 x1 = *reinterpret_cast<const float4*>(ax + 4);
            *reinterpret_cast<float4*>(out) = make_float4(
                0.35f * x0.x + 0.65f * a[0], 0.35f * x0.y + 0.65f * a[1],
                0.35f * x0.z + 0.65f * a[2], 0.35f * x0.w + 0.65f * a[3]);
            *reinterpret_cast<float4*>(out + 4) = make_float4(
                0.35f * x1.x + 0.65f * a[4], 0.35f * x1.y + 0.65f * a[5],
                0.35f * x1.z + 0.65f * a[6], 0.35f * x1.w + 0.65f * a[7]);
        } else {
            *reinterpret_cast<float4*>(out) = make_float4(a[0], a[1], a[2], a[3]);
            *reinterpret_cast<float4*>(out + 4) = make_float4(a[4], a[5], a[6], a[7]);
        }
    } else {
        __half2 o0 = __floats2half2_rn(a[0], a[1]);
        __half2 o1 = __floats2half2_rn(a[2], a[3]);
        __half2 o2 = __floats2half2_rn(a[4], a[5]);
        __half2 o3 = __floats2half2_rn(a[6], a[7]);
        uint4 pk;
        pk.x = *reinterpret_cast<unsigned*>(&o0);
        pk.y = *reinterpret_cast<unsigned*>(&o1);
        pk.z = *reinterpret_cast<unsigned*>(&o2);
        pk.w = *reinterpret_cast<unsigned*>(&o3);
        *reinterpret_cast<uint4*>((__half*)outv + (size_t)r * HD + off) = pk;
    }
}

// ---------------- weight pack: fp32 [K,N] -> fragment-layout hi/lo bf16 ----------------
__global__ __launch_bounds__(256) void pack_w(
        const float* __restrict__ W, unsigned short* __restrict__ out,
        int KS, int NS, int N) {
    int t = blockIdx.x * 256 + threadIdx.x;
    int total = KS * NS * 64;
    if (t >= total) return;
    int l = t & 63;
    int ns = (t >> 6) % NS;
    int ks = t / (64 * NS);
    int col = ns * 16 + (l & 15);
    int k0 = ks * 32 + 8 * (l >> 4);
    size_t obase = (size_t)t * 8;
    size_t pstride = (size_t)KS * NS * 512;
    #pragma unroll
    for (int e = 0; e < 8; ++e) {
        float f = W[(size_t)(k0 + e) * N + col];
        unsigned u = __float_as_uint(f);
        unsigned short h = (unsigned short)(u >> 16);
        float r = f - __uint_as_float(u & 0xFFFF0000u);
        unsigned short lo = (unsigned short)(__float_as_uint(r) >> 16);
        out[obase + e] = (unsigned short)h;
        out[pstride + obase + e] = lo;
    }
}

__device__ __forceinline__ void splitf(const float* f, bf16x8& h, bf16x8& l) {
    #pragma unroll
    for (int e = 0; e < 8; ++e) {
        unsigned u = __float_as_uint(f[e]);
        h[e] = (short)(unsigned short)(u >> 16);
        float r = f[e] - __uint_as_float(u & 0xFFFF0000u);
        l[e] = (short)(unsigned short)(__float_as_uint(r) >> 16);
    }
}

// ---------------- split-bf16 MFMA GEMM; 16-row M-tile/block, N split over 4 waves ----
// MODE 0: y = gelu(LN(A@W, gamma, beta))            (word GCN; fp16 out)
// MODE 1: out = gelu(A@W + bias)                    (gate1; A=[A1|A2])
// MODE 2: g = sigmoid(A@W + bias); out = g*aux1 + (1-g)*aux2
// MODE 3: out = LN(gelu(A@W + bias), gamma, beta)   (mlp1)
// MODE 4: v = gelu(A@W + bias); out = v @ aux1 + gamma  (mlp2 + classifier)
template<int MODE, int NS, int KS, int KSPLIT, bool A16, bool OUT16>
__global__ __launch_bounds__(256) void gemm_mfma(
        const float* __restrict__ A1, const float* __restrict__ A2,
        const unsigned short* __restrict__ Wp,
        const float* __restrict__ bias, const float* __restrict__ gamma,
        const float* __restrict__ beta,
        const float* __restrict__ aux1, const float* __restrict__ aux2,
        float* __restrict__ out, int M) {
    constexpr int N = NS * 16;
    constexpr int NSW = NS / 4;
    const int tid = threadIdx.x;
    const int wave = tid >> 6, l = tid & 63;
    const int row_base = blockIdx.x * 16;
    const int arow = row_base + (l & 15);
    const bool arow_ok = arow < M;
    const int koff = 8 * (l >> 4);
    const size_t pstride = (size_t)KS * NS * 512;

    __shared__ float ps[4][16], pq[4][16];
    __shared__ float mean_s[16], rstd_s[16];
    __shared__ float plg[4][16][2];

    f32x4 acc[NSW];
    #pragma unroll
    for (int ns = 0; ns < NSW; ++ns)
        acc[ns] = f32x4{0.f, 0.f, 0.f, 0.f};

    for (int ks = 0; ks < KS; ++ks) {
        const float* Ap;
        int ksl;
        if (ks < KSPLIT) { Ap = A1; ksl = ks; }
        else             { Ap = A2; ksl = ks - KSPLIT; }
        bf16x8 ah, al;
        if (arow_ok) {
            float f[8];
            if constexpr (A16) {
                const __half2* src = reinterpret_cast<const __half2*>(Ap)
                                     + ((size_t)arow * HD + ksl * 32 + koff) / 2;
                #pragma unroll
                for (int e = 0; e < 4; ++e) {
                    float2 v = __half22float2(src[e]);
                    f[2 * e]     = v.x;
                    f[2 * e + 1] = v.y;
                }
            } else {
                const float* src = Ap + (size_t)arow * HD + ksl * 32 + koff;
                float4 a0 = *reinterpret_cast<const float4*>(src);
                float4 a1 = *reinterpret_cast<const float4*>(src + 4);
                f[0] = a0.x; f[1] = a0.y; f[2] = a0.z; f[3] = a0.w;
                f[4] = a1.x; f[5] = a1.y; f[6] = a1.z; f[7] = a1.w;
            }
            splitf(f, ah, al);
        } else {
            #pragma unroll
            for (int e = 0; e < 8; ++e) { ah[e] = 0; al[e] = 0; }
        }
        const unsigned short* Bp = Wp + (size_t)ks * NS * 512
                                   + (size_t)wave * NSW * 512 + (size_t)l * 8;
        #pragma unroll
        for (int ns = 0; ns < NSW; ++ns) {
            bf16x8 bh = *reinterpret_cast<const bf16x8*>(Bp + ns * 512);
            bf16x8 bl = *reinterpret_cast<const bf16x8*>(Bp + pstride + ns * 512);
            acc[ns] = __builtin_amdgcn_mfma_f32_16x16x32_bf16(ah, bh, acc[ns], 0, 0, 0);
            acc[ns] = __builtin_amdgcn_mfma_f32_16x16x32_bf16(al, bh, acc[ns], 0, 0, 0);
            acc[ns] = __builtin_amdgcn_mfma_f32_16x16x32_bf16(ah, bl, acc[ns], 0, 0, 0);
        }
    }

    const int col_lane = l & 15;
    const int g4 = (l >> 4) * 4;
    constexpr float invN = 1.0f / (float)N;

    if constexpr (MODE == 0 || MODE == 3) {
        if constexpr (MODE == 3) {
            #pragma unroll
            for (int ns = 0; ns < NSW; ++ns) {
                float bb = bias[(wave * NSW + ns) * 16 + col_lane];
                #pragma unroll
                for (int r = 0; r < 4; ++r)
                    acc[ns][r] = gelu_f(acc[ns][r] + bb);
            }
        }
        float s[4] = {0.f, 0.f, 0.f, 0.f}, q[4] = {0.f, 0.f, 0.f, 0.f};
        #pragma unroll
        for (int ns = 0; ns < NSW; ++ns)
            #pragma unroll
            for (int r = 0; r < 4; ++r) {
                float v = acc[ns][r];
                s[r] += v;
                q[r] += v * v;
            }
        #pragma unroll
        for (int r = 0; r < 4; ++r) {
            #pragma unroll
            for (int m = 1; m < 16; m <<= 1) {
                s[r] += __shfl_xor(s[r], m);
                q[r] += __shfl_xor(q[r], m);
            }
        }
        if (col_lane == 0) {
            #pragma unroll
            for (int r = 0; r < 4; ++r) {
                ps[wave][g4 + r] = s[r];
                pq[wave][g4 + r] = q[r];
            }
        }
        __syncthreads();
        if (tid < 16) {
            float ss = ps[0][tid] + ps[1][tid] + ps[2][tid] + ps[3][tid];
            float qq = pq[0][tid] + pq[1][tid] + pq[2][tid] + pq[3][tid];
            float m = ss * invN;
            mean_s[tid] = m;
            rstd_s[tid] = rsqrtf(qq * invN - m * m + 1e-5f);
        }
        __syncthreads();
        #pragma unroll
        for (int ns = 0; ns < NSW; ++ns) {
            int col = (wave * NSW + ns) * 16 + col_lane;
            float gg = gamma[col], bb = beta[col];
            #pragma unroll
            for (int r = 0; r < 4; ++r) {
                int row = row_base + g4 + r;
                if (row < M) {
                    float y = (acc[ns][r] - mean_s[g4 + r]) * rstd_s[g4 + r] * gg + bb;
                    if constexpr (MODE == 0) {
                        y = gelu_f(y);
                        if constexpr (OUT16)
                            reinterpret_cast<__half*>(out)[(size_t)row * N + col] =
                                __float2half(y);
                        else
                            out[(size_t)row * N + col] = y;
                    } else {
                        out[(size_t)row * N + col] = y;
                    }
                }
            }
        }
    } else if constexpr (MODE == 1) {
        #pragma unroll
        for (int ns = 0; ns < NSW; ++ns) {
            int col = (wave * NSW + ns) * 16 + col_lane;
            float bb = bias[col];
            #pragma unroll
            for (int r = 0; r < 4; ++r) {
                int row = row_base + g4 + r;
                if (row < M)
                    out[(size_t)row * N + col] = gelu_f(acc[ns][r] + bb);
            }
        }
    } else if constexpr (MODE == 2) {
        #pragma unroll
        for (int ns = 0; ns < NSW; ++ns) {
            int col = (wave * NSW + ns) * 16 + col_lane;
            float bb = bias[col];
            #pragma unroll
            for (int r = 0; r < 4; ++r) {
                int row = row_base + g4 + r;
                if (row < M) {
                    float g = sigmoid_f(acc[ns][r] + bb);
                    float h1 = aux1[(size_t)row * N + col];
                    float h0 = aux2[(size_t)row * N + col];
                    out[(size_t)row * N + col] = g * h1 + (1.0f - g) * h0;
                }
            }
        }
    } else if constexpr (MODE == 4) {
        float lg0[4] = {0.f, 0.f, 0.f, 0.f}, lg1[4] = {0.f, 0.f, 0.f, 0.f};
        #pragma unroll
        for (int ns = 0; ns < NSW; ++ns) {
            int col = (wave * NSW + ns) * 16 + col_lane;
            float bb = bias[col];
            float c0 = aux1[col * 2 + 0];
            float c1 = aux1[col * 2 + 1];
            #pragma unroll
            for (int r = 0; r < 4; ++r) {
                float v = gelu_f(acc[ns][r] + bb);
                lg0[r] = fmaf(v, c0, lg0[r]);
                lg1[r] = fmaf(v, c1, lg1[r]);
            }
        }
        #pragma unroll
        for (int r = 0; r < 4; ++r) {
            #pragma unroll
            for (int m = 1; m < 16; m <<= 1) {
                lg0[r] += __shfl_xor(lg0[r], m);
                lg1[r] += __shfl_xor(lg1[r], m);
            }
        }
        if (col_lane == 0) {
            #pragma unroll
            for (int r = 0; r < 4; ++r) {
                plg[wave][g4 + r][0] = lg0[r];
                plg[wave][g4 + r][1] = lg1[r];
            }
        }
        __syncthreads();
        if (tid < 32) {
            int rloc = tid >> 1, c = tid & 1;
            int row = row_base + rloc;
            if (row < M) {
                float t = plg[0][rloc][c] + plg[1][rloc][c]
                        + plg[2][rloc][c] + plg[3][rloc][c];
                out[(size_t)row * 2 + c] = t + gamma[c];
            }
        }
    }
}

static void build_csr(const int* rows, const int* cols, const float* vals,
                      int nnz, int n, int* rp, int2* ev,
                      int* cnt, int* bsum, int* boff, hipStream_t stream) {
    hipMemsetAsync(cnt, 0, (size_t)n * sizeof(int), stream);
    hist_rows<<<(nnz + 255) / 256, 256, 0, stream>>>(rows, cnt, nnz);
    int nb = (n + 255) / 256;
    scan_local<<<nb, 256, 0, stream>>>(cnt, rp, bsum, n);
    scan_bsums<<<1, 256, 0, stream>>>(bsum, boff, nb, rp + n);
    scan_add<<<nb, 256, 0, stream>>>(rp, boff, n);
    hipMemsetAsync(cnt, 0, (size_t)n * sizeof(int), stream);
    csr_scatter<<<(nnz + 255) / 256, 256, 0, stream>>>(rows, cols, vals, rp, cnt, ev, nnz);
}

extern "C" void kernel_launch(void* const* d_in, const int* in_sizes, int n_in,
                              void* d_out, int out_size, void* d_ws, size_t ws_size,
                              hipStream_t stream) {
    const int*   A_rows = (const int*)  d_in[0];
    const int*   A_cols = (const int*)  d_in[1];
    const float* A_vals = (const float*)d_in[2];
    const int*   X_rows = (const int*)  d_in[3];
    const int*   X_cols = (const int*)  d_in[4];
    const float* X_vals = (const float*)d_in[5];
    const float* emb    = (const float*)d_in[7];
    const float* W1     = (const float*)d_in[8];
    const float* W2     = (const float*)d_in[9];
    const float* W3     = (const float*)d_in[10];
    const float* g1     = (const float*)d_in[11];
    const float* b1     = (const float*)d_in[12];
    const float* g2     = (const float*)d_in[13];
    const float* b2     = (const float*)d_in[14];
    const float* g3     = (const float*)d_in[15];
    const float* b3     = (const float*)d_in[16];
    const float* mW1    = (const float*)d_in[17];
    const float* mb1    = (const float*)d_in[18];
    const float* mg     = (const float*)d_in[19];
    const float* mbn    = (const float*)d_in[20];
    const float* mW2    = (const float*)d_in[21];
    const float* mb2    = (const float*)d_in[22];
    const float* cW     = (const float*)d_in[23];
    const float* cb     = (const float*)d_in[24];
    const float* gW1    = (const float*)d_in[25];
    const float* gb1    = (const float*)d_in[26];
    const float* gW2    = (const float*)d_in[27];
    const float* gb2    = (const float*)d_in[28];

    const int E_   = in_sizes[0];
    const int NNZ_ = in_sizes[3];
    const int N_   = in_sizes[7] / HD;
    const int D_   = out_size / 2;

    // ---- workspace layout ----
    __half2* emb16 = (__half2*)d_ws;                   // [N,H] fp16 | later t1 [D,H] f32
    __half2* Ba    = emb16 + (size_t)N_ * HHD;         // ping     | later docH/un f32
    __half2* Bb    = Ba    + (size_t)N_ * HHD;         // pong     | later dmix f32
    float* docH0 = (float*)(Bb + (size_t)N_ * HHD);    // [D,H] f32
    int*   A_rp = (int*)(docH0 + (size_t)D_ * HD);
    int2*  A_ev = (int2*)(A_rp + N_ + 2);              // N_ even -> 8B aligned
    int*   X_rp = (int*)(A_ev + E_);
    int2*  X_ev = (int2*)(X_rp + D_ + 2);
    int*   cnt  = (int*)(X_ev + NNZ_);
    int*   bsum = cnt + N_;
    int*   boff = bsum + 256;
    size_t pk_off = ((size_t)(boff + 256 - (int*)d_ws) + 7) & ~(size_t)7;
    unsigned short* packs = (unsigned short*)((float*)d_ws + pk_off);
    const size_t SZ_SQ = (size_t)2 * HD * HD;
    unsigned short* p_W1  = packs;
    unsigned short* p_W2  = p_W1  + SZ_SQ;
    unsigned short* p_W3  = p_W2  + SZ_SQ;
    unsigned short* p_gW2 = p_W3  + SZ_SQ;
    unsigned short* p_mW1 = p_gW2 + SZ_SQ;
    unsigned short* p_gW1 = p_mW1 + SZ_SQ;
    unsigned short* p_mW2 = p_gW1 + (size_t)2 * 2 * HD * HD;

    // doc-phase fp32 aliases
    float* docH  = (float*)Ba;
    float* t1    = (float*)emb16;
    float* dmix  = (float*)Bb;
    float* un    = (float*)Ba;
    float* logits = (float*)d_out;

    const int word_grid = (N_ + 15) / 16;
    const int doc_grid  = (D_ + 15) / 16;
    const int spmm_word_grid = 8 * ((N_ + 63) / 64);
    const int spmm_doc_grid  = 8 * ((D_ + 63) / 64);

    // ---- pack weights ----
    pack_w<<<(12 * 24 * 64 + 255) / 256, 256, 0, stream>>>(W1,  p_W1,  12, 24, HD);
    pack_w<<<(12 * 24 * 64 + 255) / 256, 256, 0, stream>>>(W2,  p_W2,  12, 24, HD);
    pack_w<<<(12 * 24 * 64 + 255) / 256, 256, 0, stream>>>(W3,  p_W3,  12, 24, HD);
    pack_w<<<(12 * 24 * 64 + 255) / 256, 256, 0, stream>>>(gW2, p_gW2, 12, 24, HD);
    pack_w<<<(12 * 24 * 64 + 255) / 256, 256, 0, stream>>>(mW1, p_mW1, 12, 24, HD);
    pack_w<<<(24 * 24 * 64 + 255) / 256, 256, 0, stream>>>(gW1, p_gW1, 24, 24, HD);
    pack_w<<<(12 * 12 * 64 + 255) / 256, 256, 0, stream>>>(mW2, p_mW2, 12, 12, HHD);

    // ---- emb -> fp16 ----
    cvt_fp16<<<((N_ * HHD) + 255) / 256, 256, 0, stream>>>(emb, emb16, N_ * HHD);

    // ---- build CSR (interleaved col/val edges) ----
    build_csr(A_rows, A_cols, A_vals, E_, N_, A_rp, A_ev, cnt, bsum, boff, stream);
    build_csr(X_rows, X_cols, X_vals, NNZ_, D_, X_rp, X_ev, cnt, bsum, boff, stream);

    // ---- GCN blocks (fp16 ping-pong; XCD-sliced gathers) ----
    spmm_sliced<false, false><<<spmm_word_grid, 384, 0, stream>>>(
        A_rp, A_ev, (const __half*)emb16, (void*)Ba, nullptr, N_);
    gemm_mfma<0, 24, 12, 12, true, true><<<word_grid, 256, 0, stream>>>(
        (const float*)Ba, nullptr, p_W1, nullptr, g1, b1, nullptr, nullptr, (float*)Bb, N_);
    spmm_sliced<false, false><<<spmm_word_grid, 384, 0, stream>>>(
        A_rp, A_ev, (const __half*)Bb, (void*)Ba, nullptr, N_);
    gemm_mfma<0, 24, 12, 12, true, true><<<word_grid, 256, 0, stream>>>(
        (const float*)Ba, nullptr, p_W2, nullptr, g2, b2, nullptr, nullptr, (float*)Bb, N_);
    spmm_sliced<false, false><<<spmm_word_grid, 384, 0, stream>>>(
        A_rp, A_ev, (const __half*)Bb, (void*)Ba, nullptr, N_);
    gemm_mfma<0, 24, 12, 12, true, true><<<word_grid, 256, 0, stream>>>(
        (const float*)Ba, nullptr, p_W3, nullptr, g3, b3, nullptr, nullptr, (float*)Bb, N_);

    // ---- doc aggregation: two sliced passes (each 3.84MB/XCD working set) ----
    // pass 1: docH0 = X @ emb
    spmm_sliced<true, false><<<spmm_doc_grid, 384, 0, stream>>>(
        X_rp, X_ev, (const __half*)emb16, (void*)docH0, nullptr, D_);
    // pass 2: docH = 0.35*docH0 + 0.65*(X @ h3)
    spmm_sliced<true, true><<<spmm_doc_grid, 384, 0, stream>>>(
        X_rp, X_ev, (const __half*)Bb, (void*)docH, docH0, D_);

    // ---- doc head ----
    gemm_mfma<1, 24, 24, 12, false, false><<<doc_grid, 256, 0, stream>>>(
        docH, docH0, p_gW1, gb1, nullptr, nullptr, nullptr, nullptr, t1, D_);
    gemm_mfma<2, 24, 12, 12, false, false><<<doc_grid, 256, 0, stream>>>(
        t1, nullptr, p_gW2, gb2, nullptr, nullptr, docH, docH0, dmix, D_);
    gemm_mfma<3, 24, 12, 12, false, false><<<doc_grid, 256, 0, stream>>>(
        dmix, nullptr, p_mW1, mb1, mg, mbn, nullptr, nullptr, un, D_);
    gemm_mfma<4, 12, 12, 12, false, false><<<doc_grid, 256, 0, stream>>>(
        un, nullptr, p_mW2, mb2, cb, nullptr, cW, nullptr, logits, D_);
}

// Round 13
// 1076.114 us; speedup vs baseline: 1.3276x; 1.3276x over previous
//
#include <hip/hip_runtime.h>
#include <hip/hip_fp16.h>

#define HD 384
#define HHD 192
#define TPR 96
#define RPB 4
#define ECHUNK 128

using bf16x8 = __attribute__((ext_vector_type(8))) short;
using f32x4  = __attribute__((ext_vector_type(4))) float;

__device__ __forceinline__ float gelu_f(float x) {
    return 0.5f * x * (1.0f + erff(x * 0.70710678118654752f));
}

__device__ __forceinline__ float sigmoid_f(float x) {
    return 1.0f / (1.0f + expf(-x));
}

__device__ __forceinline__ void ld_h4(const __half2* p, float2& lo, float2& hi) {
    uint2 raw = *reinterpret_cast<const uint2*>(p);
    lo = __half22float2(*reinterpret_cast<const __half2*>(&raw.x));
    hi = __half22float2(*reinterpret_cast<const __half2*>(&raw.y));
}

// ---------------- batched CSR build (A and X graphs in one pass) ----------------
__global__ __launch_bounds__(256) void hist2(
        const int* __restrict__ rowsA, int nA, int* __restrict__ cntA,
        const int* __restrict__ rowsX, int nX, int* __restrict__ cntX) {
    int e = blockIdx.x * 256 + threadIdx.x;
    if (e < nA) atomicAdd(&cntA[rowsA[e]], 1);
    else if (e - nA < nX) atomicAdd(&cntX[rowsX[e - nA]], 1);
}

__global__ __launch_bounds__(256) void scan_local2(
        const int* __restrict__ cntA, int* __restrict__ rpA,
        int* __restrict__ bsumA, int nA, int nbA,
        const int* __restrict__ cntX, int* __restrict__ rpX,
        int* __restrict__ bsumX, int nX) {
    __shared__ int wsum[4];
    const int* cnt; int* rp; int* bsum; int n; int lb;
    if ((int)blockIdx.x < nbA) { cnt = cntA; rp = rpA; bsum = bsumA; n = nA; lb = blockIdx.x; }
    else { cnt = cntX; rp = rpX; bsum = bsumX; n = nX; lb = blockIdx.x - nbA; }
    int i = lb * 256 + threadIdx.x;
    int lane = threadIdx.x & 63, wv = threadIdx.x >> 6;
    int v = (i < n) ? cnt[i] : 0;
    int s = v;
    #pragma unroll
    for (int o = 1; o < 64; o <<= 1) {
        int t = __shfl_up(s, o);
        if (lane >= o) s += t;
    }
    if (lane == 63) wsum[wv] = s;
    __syncthreads();
    int woff = 0;
    for (int w = 0; w < wv; ++w) woff += wsum[w];
    if (i < n) rp[i] = woff + s - v;
    if (threadIdx.x == 255) bsum[lb] = woff + s;
}

__global__ __launch_bounds__(256) void scan_bsums2(
        const int* __restrict__ bsumA, int* __restrict__ boffA, int nbA, int* totA,
        const int* __restrict__ bsumX, int* __restrict__ boffX, int nbX, int* totX) {
    __shared__ int tmp[256];
    const int* bsum; int* boff; int nb; int* tot;
    if (blockIdx.x == 0) { bsum = bsumA; boff = boffA; nb = nbA; tot = totA; }
    else                 { bsum = bsumX; boff = boffX; nb = nbX; tot = totX; }
    int tid = threadIdx.x;
    int v = (tid < nb) ? bsum[tid] : 0;
    tmp[tid] = v;
    __syncthreads();
    for (int o = 1; o < 256; o <<= 1) {
        int t = (tid >= o) ? tmp[tid - o] : 0;
        __syncthreads();
        tmp[tid] += t;
        __syncthreads();
    }
    if (tid < nb) boff[tid] = tmp[tid] - v;
    if (tid == nb - 1) *tot = tmp[tid];
}

__global__ __launch_bounds__(256) void scan_add2(
        int* __restrict__ rpA, const int* __restrict__ boffA, int nA, int nbA,
        int* __restrict__ rpX, const int* __restrict__ boffX, int nX) {
    int b = blockIdx.x;
    int* rp; const int* boff; int n; int lb;
    if (b < nbA) { rp = rpA; boff = boffA; n = nA; lb = b; }
    else         { rp = rpX; boff = boffX; n = nX; lb = b - nbA; }
    int i = lb * 256 + threadIdx.x;
    if (i < n) rp[i] += boff[lb];
}

__global__ __launch_bounds__(256) void scatter2(
        const int* __restrict__ rowsA, const int* __restrict__ colsA,
        const float* __restrict__ valsA, const int* __restrict__ rpA,
        int* __restrict__ fillA, int* __restrict__ cpA, float* __restrict__ vpA, int nA,
        const int* __restrict__ rowsX, const int* __restrict__ colsX,
        const float* __restrict__ valsX, const int* __restrict__ rpX,
        int* __restrict__ fillX, int* __restrict__ cpX, float* __restrict__ vpX, int nX) {
    int e = blockIdx.x * 256 + threadIdx.x;
    if (e < nA) {
        int r = rowsA[e];
        int pos = rpA[r] + atomicAdd(&fillA[r], 1);
        cpA[pos] = colsA[e];
        vpA[pos] = valsA[e];
    } else if ((e -= nA) < nX) {
        int r = rowsX[e];
        int pos = rpX[r] + atomicAdd(&fillX[r], 1);
        cpX[pos] = colsX[e];
        vpX[pos] = valsX[e];
    }
}

// ---------------- fused weight pack (7 weights) + emb->fp16 cvt ----------------
__device__ __forceinline__ void pack_one(
        const float* __restrict__ W, unsigned short* __restrict__ out,
        int KS, int NS, int N, int t) {
    int l = t & 63;
    int ns = (t >> 6) % NS;
    int ks = t / (64 * NS);
    int col = ns * 16 + (l & 15);
    int k0 = ks * 32 + 8 * (l >> 4);
    size_t obase = (size_t)t * 8;
    size_t pstride = (size_t)KS * NS * 512;
    #pragma unroll
    for (int e = 0; e < 8; ++e) {
        float f = W[(size_t)(k0 + e) * N + col];
        unsigned u = __float_as_uint(f);
        unsigned short h = (unsigned short)(u >> 16);
        float r = f - __uint_as_float(u & 0xFFFF0000u);
        unsigned short lo = (unsigned short)(__float_as_uint(r) >> 16);
        out[obase + e] = (unsigned short)h;
        out[pstride + obase + e] = lo;
    }
}

__global__ __launch_bounds__(256) void pack_all(
        const float* __restrict__ W1, const float* __restrict__ W2,
        const float* __restrict__ W3, const float* __restrict__ gW2,
        const float* __restrict__ mW1, const float* __restrict__ gW1,
        const float* __restrict__ mW2,
        unsigned short* __restrict__ p_W1, unsigned short* __restrict__ p_W2,
        unsigned short* __restrict__ p_W3, unsigned short* __restrict__ p_gW2,
        unsigned short* __restrict__ p_mW1, unsigned short* __restrict__ p_gW1,
        unsigned short* __restrict__ p_mW2,
        const float* __restrict__ emb, __half2* __restrict__ emb16, int n2) {
    long long t = (long long)blockIdx.x * 256 + threadIdx.x;
    const int SQ = 12 * 24 * 64;
    if (t < 5LL * SQ) {
        int w = (int)(t / SQ), i = (int)(t % SQ);
        const float* s = (w == 0) ? W1 : (w == 1) ? W2 : (w == 2) ? W3
                        : (w == 3) ? gW2 : mW1;
        unsigned short* d = (w == 0) ? p_W1 : (w == 1) ? p_W2 : (w == 2) ? p_W3
                        : (w == 3) ? p_gW2 : p_mW1;
        pack_one(s, d, 12, 24, HD, i);
        return;
    }
    t -= 5LL * SQ;
    if (t < 24 * 24 * 64) { pack_one(gW1, p_gW1, 24, 24, HD, (int)t); return; }
    t -= 24 * 24 * 64;
    if (t < 12 * 12 * 64) { pack_one(mW2, p_mW2, 12, 12, HHD, (int)t); return; }
    t -= 12 * 12 * 64;
    if (t < n2) {
        float2 v = reinterpret_cast<const float2*>(emb)[t];
        emb16[t] = __floats2half2_rn(v.x, v.y);
    }
}

// ---------------- SpMM (CSR gather, fp16 table, fp16 out) — round-9 proven ----
__global__ __launch_bounds__(384) void spmm_h2(
        const int* __restrict__ rp, const int* __restrict__ cp,
        const float* __restrict__ vp, const __half2* __restrict__ in,
        __half2* __restrict__ out, int nrows) {
    __shared__ int   lc[RPB][ECHUNK];
    __shared__ float lv[RPB][ECHUNK];
    __shared__ int maxlen_s;
    const int rr = threadIdx.x / TPR;
    const int t  = threadIdx.x % TPR;
    const int r  = blockIdx.x * RPB + rr;
    int s = 0, len = 0;
    if (r < nrows) { s = rp[r]; len = rp[r + 1] - s; }
    if (threadIdx.x == 0) maxlen_s = 0;
    __syncthreads();
    if (t == 0) atomicMax(&maxlen_s, len);
    __syncthreads();
    const int nch = (maxlen_s + ECHUNK - 1) / ECHUNK;
    float a0 = 0.f, a1 = 0.f, a2 = 0.f, a3 = 0.f;
    for (int ch = 0; ch < nch; ++ch) {
        const int base = ch * ECHUNK;
        const int tile = min(ECHUNK, len - base);
        for (int i = t; i < tile; i += TPR) {
            lc[rr][i] = cp[s + base + i];
            lv[rr][i] = vp[s + base + i];
        }
        __syncthreads();
        int p = 0;
        for (; p + 4 <= tile; p += 4) {
            int   c0 = lc[rr][p],     c1 = lc[rr][p + 1];
            int   c2 = lc[rr][p + 2], c3 = lc[rr][p + 3];
            float v0 = lv[rr][p],     v1 = lv[rr][p + 1];
            float v2 = lv[rr][p + 2], v3 = lv[rr][p + 3];
            float2 x0l, x0h, x1l, x1h, x2l, x2h, x3l, x3h;
            ld_h4(in + (size_t)c0 * HHD + 2 * t, x0l, x0h);
            ld_h4(in + (size_t)c1 * HHD + 2 * t, x1l, x1h);
            ld_h4(in + (size_t)c2 * HHD + 2 * t, x2l, x2h);
            ld_h4(in + (size_t)c3 * HHD + 2 * t, x3l, x3h);
            a0 = fmaf(v0, x0l.x, a0); a1 = fmaf(v0, x0l.y, a1);
            a2 = fmaf(v0, x0h.x, a2); a3 = fmaf(v0, x0h.y, a3);
            a0 = fmaf(v1, x1l.x, a0); a1 = fmaf(v1, x1l.y, a1);
            a2 = fmaf(v1, x1h.x, a2); a3 = fmaf(v1, x1h.y, a3);
            a0 = fmaf(v2, x2l.x, a0); a1 = fmaf(v2, x2l.y, a1);
            a2 = fmaf(v2, x2h.x, a2); a3 = fmaf(v2, x2h.y, a3);
            a0 = fmaf(v3, x3l.x, a0); a1 = fmaf(v3, x3l.y, a1);
            a2 = fmaf(v3, x3h.x, a2); a3 = fmaf(v3, x3h.y, a3);
        }
        for (; p < tile; ++p) {
            int c = lc[rr][p];
            float v = lv[rr][p];
            float2 xl, xh;
            ld_h4(in + (size_t)c * HHD + 2 * t, xl, xh);
            a0 = fmaf(v, xl.x, a0); a1 = fmaf(v, xl.y, a1);
            a2 = fmaf(v, xh.x, a2); a3 = fmaf(v, xh.y, a3);
        }
        __syncthreads();
    }
    if (r < nrows) {
        __half2 o0 = __floats2half2_rn(a0, a1);
        __half2 o1 = __floats2half2_rn(a2, a3);
        uint2 packed;
        packed.x = *reinterpret_cast<unsigned*>(&o0);
        packed.y = *reinterpret_cast<unsigned*>(&o1);
        *reinterpret_cast<uint2*>(out + (size_t)r * HHD + 2 * t) = packed;
    }
}

// ---------------- fused doc SpMM: docH0 = X@emb, docH = 0.35*docH0 + 0.65*X@h3 ----
__global__ __launch_bounds__(384) void spmm_doc2(
        const int* __restrict__ rp, const int* __restrict__ cp,
        const float* __restrict__ vp,
        const __half2* __restrict__ inH, const __half2* __restrict__ inE,
        float* __restrict__ docH, float* __restrict__ docH0, int nrows) {
    __shared__ int   lc[RPB][ECHUNK];
    __shared__ float lv[RPB][ECHUNK];
    __shared__ int maxlen_s;
    const int rr = threadIdx.x / TPR;
    const int t  = threadIdx.x % TPR;
    const int r  = blockIdx.x * RPB + rr;
    int s = 0, len = 0;
    if (r < nrows) { s = rp[r]; len = rp[r + 1] - s; }
    if (threadIdx.x == 0) maxlen_s = 0;
    __syncthreads();
    if (t == 0) atomicMax(&maxlen_s, len);
    __syncthreads();
    const int nch = (maxlen_s + ECHUNK - 1) / ECHUNK;
    float h0 = 0.f, h1 = 0.f, h2 = 0.f, h3 = 0.f;
    float e0 = 0.f, e1 = 0.f, e2 = 0.f, e3 = 0.f;
    for (int ch = 0; ch < nch; ++ch) {
        const int base = ch * ECHUNK;
        const int tile = min(ECHUNK, len - base);
        for (int i = t; i < tile; i += TPR) {
            lc[rr][i] = cp[s + base + i];
            lv[rr][i] = vp[s + base + i];
        }
        __syncthreads();
        int p = 0;
        for (; p + 2 <= tile; p += 2) {
            int   c0 = lc[rr][p], c1 = lc[rr][p + 1];
            float v0 = lv[rr][p], v1 = lv[rr][p + 1];
            float2 ha0, hb0, ea0, eb0, ha1, hb1, ea1, eb1;
            ld_h4(inH + (size_t)c0 * HHD + 2 * t, ha0, hb0);
            ld_h4(inE + (size_t)c0 * HHD + 2 * t, ea0, eb0);
            ld_h4(inH + (size_t)c1 * HHD + 2 * t, ha1, hb1);
            ld_h4(inE + (size_t)c1 * HHD + 2 * t, ea1, eb1);
            h0 = fmaf(v0, ha0.x, h0); h1 = fmaf(v0, ha0.y, h1);
            h2 = fmaf(v0, hb0.x, h2); h3 = fmaf(v0, hb0.y, h3);
            e0 = fmaf(v0, ea0.x, e0); e1 = fmaf(v0, ea0.y, e1);
            e2 = fmaf(v0, eb0.x, e2); e3 = fmaf(v0, eb0.y, e3);
            h0 = fmaf(v1, ha1.x, h0); h1 = fmaf(v1, ha1.y, h1);
            h2 = fmaf(v1, hb1.x, h2); h3 = fmaf(v1, hb1.y, h3);
            e0 = fmaf(v1, ea1.x, e0); e1 = fmaf(v1, ea1.y, e1);
            e2 = fmaf(v1, eb1.x, e2); e3 = fmaf(v1, eb1.y, e3);
        }
        for (; p < tile; ++p) {
            int c = lc[rr][p];
            float v = lv[rr][p];
            float2 ha, hb, ea, eb;
            ld_h4(inH + (size_t)c * HHD + 2 * t, ha, hb);
            ld_h4(inE + (size_t)c * HHD + 2 * t, ea, eb);
            h0 = fmaf(v, ha.x, h0); h1 = fmaf(v, ha.y, h1);
            h2 = fmaf(v, hb.x, h2); h3 = fmaf(v, hb.y, h3);
            e0 = fmaf(v, ea.x, e0); e1 = fmaf(v, ea.y, e1);
            e2 = fmaf(v, eb.x, e2); e3 = fmaf(v, eb.y, e3);
        }
        __syncthreads();
    }
    if (r < nrows) {
        float4 ev = make_float4(e0, e1, e2, e3);
        float4 hv = make_float4(0.35f * e0 + 0.65f * h0, 0.35f * e1 + 0.65f * h1,
                                0.35f * e2 + 0.65f * h2, 0.35f * e3 + 0.65f * h3);
        *reinterpret_cast<float4*>(docH0 + (size_t)r * HD + 4 * t) = ev;
        *reinterpret_cast<float4*>(docH  + (size_t)r * HD + 4 * t) = hv;
    }
}

__device__ __forceinline__ void splitf(const float* f, bf16x8& h, bf16x8& l) {
    #pragma unroll
    for (int e = 0; e < 8; ++e) {
        unsigned u = __float_as_uint(f[e]);
        h[e] = (short)(unsigned short)(u >> 16);
        float r = f[e] - __uint_as_float(u & 0xFFFF0000u);
        l[e] = (short)(unsigned short)(__float_as_uint(r) >> 16);
    }
}

// ---------------- split-bf16 MFMA GEMM; 16-row M-tile/block, N split over 4 waves ----
// MODE 0: y = gelu(LN(A@W, gamma, beta))            (word GCN; fp16 out)
// MODE 1: out = gelu(A@W + bias)                    (gate1; A=[A1|A2])
// MODE 2: g = sigmoid(A@W + bias); out = g*aux1 + (1-g)*aux2
// MODE 3: out = LN(gelu(A@W + bias), gamma, beta)   (mlp1)
// MODE 4: v = gelu(A@W + bias); out = v @ aux1 + gamma  (mlp2 + classifier)
template<int MODE, int NS, int KS, int KSPLIT, bool A16, bool OUT16>
__global__ __launch_bounds__(256) void gemm_mfma(
        const float* __restrict__ A1, const float* __restrict__ A2,
        const unsigned short* __restrict__ Wp,
        const float* __restrict__ bias, const float* __restrict__ gamma,
        const float* __restrict__ beta,
        const float* __restrict__ aux1, const float* __restrict__ aux2,
        float* __restrict__ out, int M) {
    constexpr int N = NS * 16;
    constexpr int NSW = NS / 4;
    const int tid = threadIdx.x;
    const int wave = tid >> 6, l = tid & 63;
    const int row_base = blockIdx.x * 16;
    const int arow = row_base + (l & 15);
    const bool arow_ok = arow < M;
    const int koff = 8 * (l >> 4);
    const size_t pstride = (size_t)KS * NS * 512;

    __shared__ float ps[4][16], pq[4][16];
    __shared__ float mean_s[16], rstd_s[16];
    __shared__ float plg[4][16][2];

    f32x4 acc[NSW];
    #pragma unroll
    for (int ns = 0; ns < NSW; ++ns)
        acc[ns] = f32x4{0.f, 0.f, 0.f, 0.f};

    for (int ks = 0; ks < KS; ++ks) {
        const float* Ap;
        int ksl;
        if (ks < KSPLIT) { Ap = A1; ksl = ks; }
        else             { Ap = A2; ksl = ks - KSPLIT; }
        bf16x8 ah, al;
        if (arow_ok) {
            float f[8];
            if constexpr (A16) {
                const __half2* src = reinterpret_cast<const __half2*>(Ap)
                                     + ((size_t)arow * HD + ksl * 32 + koff) / 2;
                #pragma unroll
                for (int e = 0; e < 4; ++e) {
                    float2 v = __half22float2(src[e]);
                    f[2 * e]     = v.x;
                    f[2 * e + 1] = v.y;
                }
            } else {
                const float* src = Ap + (size_t)arow * HD + ksl * 32 + koff;
                float4 a0 = *reinterpret_cast<const float4*>(src);
                float4 a1 = *reinterpret_cast<const float4*>(src + 4);
                f[0] = a0.x; f[1] = a0.y; f[2] = a0.z; f[3] = a0.w;
                f[4] = a1.x; f[5] = a1.y; f[6] = a1.z; f[7] = a1.w;
            }
            splitf(f, ah, al);
        } else {
            #pragma unroll
            for (int e = 0; e < 8; ++e) { ah[e] = 0; al[e] = 0; }
        }
        const unsigned short* Bp = Wp + (size_t)ks * NS * 512
                                   + (size_t)wave * NSW * 512 + (size_t)l * 8;
        #pragma unroll
        for (int ns = 0; ns < NSW; ++ns) {
            bf16x8 bh = *reinterpret_cast<const bf16x8*>(Bp + ns * 512);
            bf16x8 bl = *reinterpret_cast<const bf16x8*>(Bp + pstride + ns * 512);
            acc[ns] = __builtin_amdgcn_mfma_f32_16x16x32_bf16(ah, bh, acc[ns], 0, 0, 0);
            acc[ns] = __builtin_amdgcn_mfma_f32_16x16x32_bf16(al, bh, acc[ns], 0, 0, 0);
            acc[ns] = __builtin_amdgcn_mfma_f32_16x16x32_bf16(ah, bl, acc[ns], 0, 0, 0);
        }
    }

    const int col_lane = l & 15;
    const int g4 = (l >> 4) * 4;
    constexpr float invN = 1.0f / (float)N;

    if constexpr (MODE == 0 || MODE == 3) {
        if constexpr (MODE == 3) {
            #pragma unroll
            for (int ns = 0; ns < NSW; ++ns) {
                float bb = bias[(wave * NSW + ns) * 16 + col_lane];
                #pragma unroll
                for (int r = 0; r < 4; ++r)
                    acc[ns][r] = gelu_f(acc[ns][r] + bb);
            }
        }
        float s[4] = {0.f, 0.f, 0.f, 0.f}, q[4] = {0.f, 0.f, 0.f, 0.f};
        #pragma unroll
        for (int ns = 0; ns < NSW; ++ns)
            #pragma unroll
            for (int r = 0; r < 4; ++r) {
                float v = acc[ns][r];
                s[r] += v;
                q[r] += v * v;
            }
        #pragma unroll
        for (int r = 0; r < 4; ++r) {
            #pragma unroll
            for (int m = 1; m < 16; m <<= 1) {
                s[r] += __shfl_xor(s[r], m);
                q[r] += __shfl_xor(q[r], m);
            }
        }
        if (col_lane == 0) {
            #pragma unroll
            for (int r = 0; r < 4; ++r) {
                ps[wave][g4 + r] = s[r];
                pq[wave][g4 + r] = q[r];
            }
        }
        __syncthreads();
        if (tid < 16) {
            float ss = ps[0][tid] + ps[1][tid] + ps[2][tid] + ps[3][tid];
            float qq = pq[0][tid] + pq[1][tid] + pq[2][tid] + pq[3][tid];
            float m = ss * invN;
            mean_s[tid] = m;
            rstd_s[tid] = rsqrtf(qq * invN - m * m + 1e-5f);
        }
        __syncthreads();
        #pragma unroll
        for (int ns = 0; ns < NSW; ++ns) {
            int col = (wave * NSW + ns) * 16 + col_lane;
            float gg = gamma[col], bb = beta[col];
            #pragma unroll
            for (int r = 0; r < 4; ++r) {
                int row = row_base + g4 + r;
                if (row < M) {
                    float y = (acc[ns][r] - mean_s[g4 + r]) * rstd_s[g4 + r] * gg + bb;
                    if constexpr (MODE == 0) {
                        y = gelu_f(y);
                        if constexpr (OUT16)
                            reinterpret_cast<__half*>(out)[(size_t)row * N + col] =
                                __float2half(y);
                        else
                            out[(size_t)row * N + col] = y;
                    } else {
                        out[(size_t)row * N + col] = y;
                    }
                }
            }
        }
    } else if constexpr (MODE == 1) {
        #pragma unroll
        for (int ns = 0; ns < NSW; ++ns) {
            int col = (wave * NSW + ns) * 16 + col_lane;
            float bb = bias[col];
            #pragma unroll
            for (int r = 0; r < 4; ++r) {
                int row = row_base + g4 + r;
                if (row < M)
                    out[(size_t)row * N + col] = gelu_f(acc[ns][r] + bb);
            }
        }
    } else if constexpr (MODE == 2) {
        #pragma unroll
        for (int ns = 0; ns < NSW; ++ns) {
            int col = (wave * NSW + ns) * 16 + col_lane;
            float bb = bias[col];
            #pragma unroll
            for (int r = 0; r < 4; ++r) {
                int row = row_base + g4 + r;
                if (row < M) {
                    float g = sigmoid_f(acc[ns][r] + bb);
                    float h1 = aux1[(size_t)row * N + col];
                    float h0 = aux2[(size_t)row * N + col];
                    out[(size_t)row * N + col] = g * h1 + (1.0f - g) * h0;
                }
            }
        }
    } else if constexpr (MODE == 4) {
        float lg0[4] = {0.f, 0.f, 0.f, 0.f}, lg1[4] = {0.f, 0.f, 0.f, 0.f};
        #pragma unroll
        for (int ns = 0; ns < NSW; ++ns) {
            int col = (wave * NSW + ns) * 16 + col_lane;
            float bb = bias[col];
            float c0 = aux1[col * 2 + 0];
            float c1 = aux1[col * 2 + 1];
            #pragma unroll
            for (int r = 0; r < 4; ++r) {
                float v = gelu_f(acc[ns][r] + bb);
                lg0[r] = fmaf(v, c0, lg0[r]);
                lg1[r] = fmaf(v, c1, lg1[r]);
            }
        }
        #pragma unroll
        for (int r = 0; r < 4; ++r) {
            #pragma unroll
            for (int m = 1; m < 16; m <<= 1) {
                lg0[r] += __shfl_xor(lg0[r], m);
                lg1[r] += __shfl_xor(lg1[r], m);
            }
        }
        if (col_lane == 0) {
            #pragma unroll
            for (int r = 0; r < 4; ++r) {
                plg[wave][g4 + r][0] = lg0[r];
                plg[wave][g4 + r][1] = lg1[r];
            }
        }
        __syncthreads();
        if (tid < 32) {
            int rloc = tid >> 1, c = tid & 1;
            int row = row_base + rloc;
            if (row < M) {
                float t = plg[0][rloc][c] + plg[1][rloc][c]
                        + plg[2][rloc][c] + plg[3][rloc][c];
                out[(size_t)row * 2 + c] = t + gamma[c];
            }
        }
    }
}

extern "C" void kernel_launch(void* const* d_in, const int* in_sizes, int n_in,
                              void* d_out, int out_size, void* d_ws, size_t ws_size,
                              hipStream_t stream) {
    const int*   A_rows = (const int*)  d_in[0];
    const int*   A_cols = (const int*)  d_in[1];
    const float* A_vals = (const float*)d_in[2];
    const int*   X_rows = (const int*)  d_in[3];
    const int*   X_cols = (const int*)  d_in[4];
    const float* X_vals = (const float*)d_in[5];
    const float* emb    = (const float*)d_in[7];
    const float* W1     = (const float*)d_in[8];
    const float* W2     = (const float*)d_in[9];
    const float* W3     = (const float*)d_in[10];
    const float* g1     = (const float*)d_in[11];
    const float* b1     = (const float*)d_in[12];
    const float* g2     = (const float*)d_in[13];
    const float* b2     = (const float*)d_in[14];
    const float* g3     = (const float*)d_in[15];
    const float* b3     = (const float*)d_in[16];
    const float* mW1    = (const float*)d_in[17];
    const float* mb1    = (const float*)d_in[18];
    const float* mg     = (const float*)d_in[19];
    const float* mbn    = (const float*)d_in[20];
    const float* mW2    = (const float*)d_in[21];
    const float* mb2    = (const float*)d_in[22];
    const float* cW     = (const float*)d_in[23];
    const float* cb     = (const float*)d_in[24];
    const float* gW1    = (const float*)d_in[25];
    const float* gb1    = (const float*)d_in[26];
    const float* gW2    = (const float*)d_in[27];
    const float* gb2    = (const float*)d_in[28];

    const int E_   = in_sizes[0];
    const int NNZ_ = in_sizes[3];
    const int N_   = in_sizes[7] / HD;
    const int D_   = out_size / 2;

    // ---- workspace layout (round-9 proven, + split count buffers) ----
    __half2* emb16 = (__half2*)d_ws;                   // [N,H] fp16 | later t1 [D,H] f32
    __half2* Ba    = emb16 + (size_t)N_ * HHD;         // ping     | later docH/un f32
    __half2* Bb    = Ba    + (size_t)N_ * HHD;         // pong     | later dmix f32
    float* docH0 = (float*)(Bb + (size_t)N_ * HHD);    // [D,H] f32
    int*   A_rp = (int*)(docH0 + (size_t)D_ * HD);     // N+1
    int*   A_cp = A_rp + (N_ + 1);                     // E
    float* A_vp = (float*)(A_cp + E_);                 // E
    int*   X_rp = (int*)(A_vp + E_);                   // D+1
    int*   X_cp = X_rp + (D_ + 1);                     // NNZ
    float* X_vp = (float*)(X_cp + NNZ_);               // NNZ
    int*   cntA = (int*)(X_vp + NNZ_);                 // N  (adjacent to cntX for one memset)
    int*   cntX = cntA + N_;                           // D
    int*   bsumA = cntX + D_;                          // 256
    int*   bsumX = bsumA + 256;
    int*   boffA = bsumX + 256;
    int*   boffX = boffA + 256;
    size_t pk_off = ((size_t)(boffX + 256 - (int*)d_ws) + 7) & ~(size_t)7;
    unsigned short* packs = (unsigned short*)((float*)d_ws + pk_off);
    const size_t SZ_SQ = (size_t)2 * HD * HD;
    unsigned short* p_W1  = packs;
    unsigned short* p_W2  = p_W1  + SZ_SQ;
    unsigned short* p_W3  = p_W2  + SZ_SQ;
    unsigned short* p_gW2 = p_W3  + SZ_SQ;
    unsigned short* p_mW1 = p_gW2 + SZ_SQ;
    unsigned short* p_gW1 = p_mW1 + SZ_SQ;
    unsigned short* p_mW2 = p_gW1 + (size_t)2 * 2 * HD * HD;

    // doc-phase fp32 aliases
    float* docH  = (float*)Ba;
    float* t1    = (float*)emb16;
    float* dmix  = (float*)Bb;
    float* un    = (float*)Ba;
    float* logits = (float*)d_out;

    const int word_grid = (N_ + 15) / 16;
    const int doc_grid  = (D_ + 15) / 16;
    const int spmm_word_grid = (N_ + RPB - 1) / RPB;
    const int spmm_doc_grid  = (D_ + RPB - 1) / RPB;
    const int nbA = (N_ + 255) / 256;
    const int nbX = (D_ + 255) / 256;

    // ---- fused pack (7 weights) + emb->fp16 ----
    {
        long long total = 5LL * (12 * 24 * 64) + 24 * 24 * 64 + 12 * 12 * 64
                        + (long long)N_ * HHD;
        pack_all<<<(int)((total + 255) / 256), 256, 0, stream>>>(
            W1, W2, W3, gW2, mW1, gW1, mW2,
            p_W1, p_W2, p_W3, p_gW2, p_mW1, p_gW1, p_mW2,
            emb, emb16, N_ * HHD);
    }

    // ---- batched CSR build for A and X ----
    hipMemsetAsync(cntA, 0, (size_t)(N_ + D_) * sizeof(int), stream);
    {
        int tot = E_ + NNZ_;
        hist2<<<(tot + 255) / 256, 256, 0, stream>>>(A_rows, E_, cntA, X_rows, NNZ_, cntX);
        scan_local2<<<nbA + nbX, 256, 0, stream>>>(cntA, A_rp, bsumA, N_, nbA,
                                                   cntX, X_rp, bsumX, D_);
        scan_bsums2<<<2, 256, 0, stream>>>(bsumA, boffA, nbA, A_rp + N_,
                                           bsumX, boffX, nbX, X_rp + D_);
        scan_add2<<<nbA + nbX, 256, 0, stream>>>(A_rp, boffA, N_, nbA, X_rp, boffX, D_);
        hipMemsetAsync(cntA, 0, (size_t)(N_ + D_) * sizeof(int), stream);
        scatter2<<<(tot + 255) / 256, 256, 0, stream>>>(
            A_rows, A_cols, A_vals, A_rp, cntA, A_cp, A_vp, E_,
            X_rows, X_cols, X_vals, X_rp, cntX, X_cp, X_vp, NNZ_);
    }

    // ---- GCN blocks (fp16 ping-pong) ----
    spmm_h2<<<spmm_word_grid, 384, 0, stream>>>(A_rp, A_cp, A_vp, emb16, Ba, N_);
    gemm_mfma<0, 24, 12, 12, true, true><<<word_grid, 256, 0, stream>>>(
        (const float*)Ba, nullptr, p_W1, nullptr, g1, b1, nullptr, nullptr, (float*)Bb, N_);
    spmm_h2<<<spmm_word_grid, 384, 0, stream>>>(A_rp, A_cp, A_vp, Bb, Ba, N_);
    gemm_mfma<0, 24, 12, 12, true, true><<<word_grid, 256, 0, stream>>>(
        (const float*)Ba, nullptr, p_W2, nullptr, g2, b2, nullptr, nullptr, (float*)Bb, N_);
    spmm_h2<<<spmm_word_grid, 384, 0, stream>>>(A_rp, A_cp, A_vp, Bb, Ba, N_);
    gemm_mfma<0, 24, 12, 12, true, true><<<word_grid, 256, 0, stream>>>(
        (const float*)Ba, nullptr, p_W3, nullptr, g3, b3, nullptr, nullptr, (float*)Bb, N_);

    // ---- fused doc aggregation (h3 in Bb, emb16) ----
    spmm_doc2<<<spmm_doc_grid, 384, 0, stream>>>(X_rp, X_cp, X_vp, Bb, emb16,
                                                 docH, docH0, D_);

    // ---- doc head ----
    gemm_mfma<1, 24, 24, 12, false, false><<<doc_grid, 256, 0, stream>>>(
        docH, docH0, p_gW1, gb1, nullptr, nullptr, nullptr, nullptr, t1, D_);
    gemm_mfma<2, 24, 12, 12, false, false><<<doc_grid, 256, 0, stream>>>(
        t1, nullptr, p_gW2, gb2, nullptr, nullptr, docH, docH0, dmix, D_);
    gemm_mfma<3, 24, 12, 12, false, false><<<doc_grid, 256, 0, stream>>>(
        dmix, nullptr, p_mW1, mb1, mg, mbn, nullptr, nullptr, un, D_);
    gemm_mfma<4, 12, 12, 12, false, false><<<doc_grid, 256, 0, stream>>>(
        un, nullptr, p_mW2, mb2, cb, nullptr, cW, nullptr, logits, D_);
}